// Round 9
// baseline (40.084 us; speedup 1.0000x reference)
//
#include <hip/hip_runtime.h>
#include <stdint.h>

#define NF   2344
#define ACCW 8
#define NA   38
#define TPB  512

__device__ __forceinline__ unsigned short f32_to_bf16(float f) {
    unsigned u = __float_as_uint(f);
    u += 0x7FFFu + ((u >> 16) & 1u);   // round-to-nearest-even
    return (unsigned short)(u >> 16);
}
__device__ __forceinline__ float bf16_lo(unsigned u) { return __uint_as_float(u << 16); }
__device__ __forceinline__ float bf16_hi(unsigned u) { return __uint_as_float(u & 0xFFFF0000u); }

// 1 thread = 1 element, zero cross-lane traffic (LDS pipe stays at the
// 23.75 cyc/elem gather floor). Index loads: per color 9 int4 + 1 int2
// (exact 38-int cover), issued in two double-color batches with asm
// "memory" fences so hipcc can't sink them into the gather stream
// (r7 failure mode: VGPR=28, 20 serialized waits).
__global__ __launch_bounds__(TPB, 4) void nnue_fwd(
    const int* __restrict__ bfeat, const int* __restrict__ wfeat,
    const int* __restrict__ stm,
    const float* __restrict__ w1, const float* __restrict__ b1,
    const float* __restrict__ w2, const float* __restrict__ b2,
    float* __restrict__ out, int nbatch)
{
    __shared__ unsigned short tbl[NF * ACCW];   // bf16 table, 16B/row (37.5 KB)

    for (int j = threadIdx.x; j < (NF * ACCW) / 4; j += TPB) {
        float4 v = reinterpret_cast<const float4*>(w1)[j];
        unsigned lo = (unsigned)f32_to_bf16(v.x) | ((unsigned)f32_to_bf16(v.y) << 16);
        unsigned hi = (unsigned)f32_to_bf16(v.z) | ((unsigned)f32_to_bf16(v.w) << 16);
        reinterpret_cast<uint2*>(tbl)[j] = make_uint2(lo, hi);
    }
    __syncthreads();

    const int e = blockIdx.x * TPB + threadIdx.x;
    if (e >= nbatch) return;

    const char* bb = reinterpret_cast<const char*>(bfeat + (long)e * NA);
    const char* wb = reinterpret_cast<const char*>(wfeat + (long)e * NA);
    const int s = stm[e];

#define G(acc, idx) { \
        uint4 r = *reinterpret_cast<const uint4*>( \
            reinterpret_cast<const char*>(tbl) + ((unsigned)(idx) << 4)); \
        acc[0] += bf16_lo(r.x); acc[1] += bf16_hi(r.x); \
        acc[2] += bf16_lo(r.y); acc[3] += bf16_hi(r.y); \
        acc[4] += bf16_lo(r.z); acc[5] += bf16_hi(r.z); \
        acc[6] += bf16_lo(r.w); acc[7] += bf16_hi(r.w); }
#define G4(acc, v) { G(acc, v.x); G(acc, v.y); G(acc, v.z); G(acc, v.w); }

    float aB[8] = {0,0,0,0,0,0,0,0};
    float aW[8] = {0,0,0,0,0,0,0,0};

    // ---- batch 1: black[0:5], white[0:5] (10 int4 in flight) ----
    int4 b0 = *reinterpret_cast<const int4*>(bb +  0);
    int4 b1v= *reinterpret_cast<const int4*>(bb + 16);
    int4 b2v= *reinterpret_cast<const int4*>(bb + 32);
    int4 b3 = *reinterpret_cast<const int4*>(bb + 48);
    int4 b4 = *reinterpret_cast<const int4*>(bb + 64);
    int4 w0 = *reinterpret_cast<const int4*>(wb +  0);
    int4 w1v= *reinterpret_cast<const int4*>(wb + 16);
    int4 w2v= *reinterpret_cast<const int4*>(wb + 32);
    int4 w3 = *reinterpret_cast<const int4*>(wb + 48);
    int4 w4 = *reinterpret_cast<const int4*>(wb + 64);
    asm volatile("" ::: "memory");   // pin issue point of batch 1

    // gather black batch 1 (single batched vmcnt wait)
    G4(aB, b0); G4(aB, b1v); G4(aB, b2v); G4(aB, b3); G4(aB, b4);

    // ---- batch 2: black[5:10], white[5:10] ----
    int4 b5 = *reinterpret_cast<const int4*>(bb +  80);
    int4 b6 = *reinterpret_cast<const int4*>(bb +  96);
    int4 b7 = *reinterpret_cast<const int4*>(bb + 112);
    int4 b8 = *reinterpret_cast<const int4*>(bb + 128);
    int2 bt = *reinterpret_cast<const int2*>(bb + 144);
    int4 w5 = *reinterpret_cast<const int4*>(wb +  80);
    int4 w6 = *reinterpret_cast<const int4*>(wb +  96);
    int4 w7 = *reinterpret_cast<const int4*>(wb + 112);
    int4 w8 = *reinterpret_cast<const int4*>(wb + 128);
    int2 wt = *reinterpret_cast<const int2*>(wb + 144);
    asm volatile("" ::: "memory");   // pin issue point of batch 2

    // gather white batch 1 (already landed), then batch 2 both colors
    G4(aW, w0); G4(aW, w1v); G4(aW, w2v); G4(aW, w3); G4(aW, w4);
    G4(aB, b5); G4(aB, b6); G4(aB, b7); G4(aB, b8);
    G(aB, bt.x); G(aB, bt.y);
    G4(aW, w5); G4(aW, w6); G4(aW, w7); G4(aW, w8);
    G(aW, wt.x); G(aW, wt.y);
#undef G4
#undef G

    // ---- clip + stm-ordered dot (branchless: both halves per color) ----
    float dbl = 0.f, dbh = 0.f, dwl = 0.f, dwh = 0.f;
#pragma unroll
    for (int k = 0; k < 8; ++k) {
        float bv = fminf(fmaxf(aB[k] + b1[k], 0.f), 1.f);
        float wv = fminf(fmaxf(aW[k] + b1[k], 0.f), 1.f);
        dbl += bv * w2[k]; dbh += bv * w2[8 + k];
        dwl += wv * w2[k]; dwh += wv * w2[8 + k];
    }
    out[e] = b2[0] + (s == 0 ? (dbl + dwh) : (dbh + dwl));
}

extern "C" void kernel_launch(void* const* d_in, const int* in_sizes, int n_in,
                              void* d_out, int out_size, void* d_ws, size_t ws_size,
                              hipStream_t stream) {
    const int*   bfeat = (const int*)  d_in[0];
    const int*   wfeat = (const int*)  d_in[1];
    const int*   stm   = (const int*)  d_in[2];
    const float* w1    = (const float*)d_in[3];
    const float* b1    = (const float*)d_in[4];
    const float* w2    = (const float*)d_in[5];
    const float* b2    = (const float*)d_in[6];
    float* out = (float*)d_out;

    const int nbatch = in_sizes[2];
    const int grid = (nbatch + TPB - 1) / TPB;
    nnue_fwd<<<grid, TPB, 0, stream>>>(bfeat, wfeat, stm, w1, b1, w2, b2, out, nbatch);
}

// Round 10
// 23.847 us; speedup vs baseline: 1.6809x; 1.6809x over previous
//
#include <hip/hip_runtime.h>
#include <stdint.h>

#define NF   2344
#define ACCW 8
#define NA   38
#define TPB  512

__device__ __forceinline__ unsigned short f32_to_bf16(float f) {
    unsigned u = __float_as_uint(f);
    u += 0x7FFFu + ((u >> 16) & 1u);   // round-to-nearest-even
    return (unsigned short)(u >> 16);
}
__device__ __forceinline__ float bf16_lo(unsigned u) { return __uint_as_float(u << 16); }
__device__ __forceinline__ float bf16_hi(unsigned u) { return __uint_as_float(u & 0xFFFF0000u); }

#define KEEP2(v) asm volatile("" :: "v"(v.x), "v"(v.y))

// 2 threads/elem (h = t&1): 524288 threads -> 32 waves/CU (the r6 winner).
// Lane h owns int2-slots {2j+h} of BOTH colors (pair covers contiguous 16B
// per instr); tail int2 (ints 36,37) loaded by both lanes, split .x/.y.
// ALL 20 index loads issued up-front + operand-tied KEEP at gather start
// (memory-clobber fences are ignored for __restrict__ const loads - r9).
// B/W gathers interleaved; pair-combine with 8 shfl (lane h finalizes color h).
__global__ __launch_bounds__(TPB, 4) void nnue_fwd(
    const int* __restrict__ bfeat, const int* __restrict__ wfeat,
    const int* __restrict__ stm,
    const float* __restrict__ w1, const float* __restrict__ b1,
    const float* __restrict__ w2, const float* __restrict__ b2,
    float* __restrict__ out, int nbatch)
{
    __shared__ unsigned short tbl[NF * ACCW];   // bf16 table, 16B/row (37.5 KB)

    for (int j = threadIdx.x; j < (NF * ACCW) / 4; j += TPB) {
        float4 v = reinterpret_cast<const float4*>(w1)[j];
        unsigned lo = (unsigned)f32_to_bf16(v.x) | ((unsigned)f32_to_bf16(v.y) << 16);
        unsigned hi = (unsigned)f32_to_bf16(v.z) | ((unsigned)f32_to_bf16(v.w) << 16);
        reinterpret_cast<uint2*>(tbl)[j] = make_uint2(lo, hi);
    }
    __syncthreads();

    const int t = blockIdx.x * TPB + threadIdx.x;
    const int e = t >> 1;
    const int h = t & 1;
    if (e >= nbatch) return;

    const char* bb = reinterpret_cast<const char*>(bfeat + (long)e * NA);
    const char* wb = reinterpret_cast<const char*>(wfeat + (long)e * NA);

    // ---- issue ALL index loads (20 x int2 = 40 VGPR in flight) ----
    int2 bq0 = *reinterpret_cast<const int2*>(bb +   0 + 8 * h);
    int2 bq1 = *reinterpret_cast<const int2*>(bb +  16 + 8 * h);
    int2 bq2 = *reinterpret_cast<const int2*>(bb +  32 + 8 * h);
    int2 bq3 = *reinterpret_cast<const int2*>(bb +  48 + 8 * h);
    int2 bq4 = *reinterpret_cast<const int2*>(bb +  64 + 8 * h);
    int2 bq5 = *reinterpret_cast<const int2*>(bb +  80 + 8 * h);
    int2 bq6 = *reinterpret_cast<const int2*>(bb +  96 + 8 * h);
    int2 bq7 = *reinterpret_cast<const int2*>(bb + 112 + 8 * h);
    int2 bq8 = *reinterpret_cast<const int2*>(bb + 128 + 8 * h);
    int2 bt  = *reinterpret_cast<const int2*>(bb + 144);
    int2 wq0 = *reinterpret_cast<const int2*>(wb +   0 + 8 * h);
    int2 wq1 = *reinterpret_cast<const int2*>(wb +  16 + 8 * h);
    int2 wq2 = *reinterpret_cast<const int2*>(wb +  32 + 8 * h);
    int2 wq3 = *reinterpret_cast<const int2*>(wb +  48 + 8 * h);
    int2 wq4 = *reinterpret_cast<const int2*>(wb +  64 + 8 * h);
    int2 wq5 = *reinterpret_cast<const int2*>(wb +  80 + 8 * h);
    int2 wq6 = *reinterpret_cast<const int2*>(wb +  96 + 8 * h);
    int2 wq7 = *reinterpret_cast<const int2*>(wb + 112 + 8 * h);
    int2 wq8 = *reinterpret_cast<const int2*>(wb + 128 + 8 * h);
    int2 wt  = *reinterpret_cast<const int2*>(wb + 144);
    // operand-tie: force all loads resident HERE (one batched s_waitcnt)
    KEEP2(bq0); KEEP2(bq1); KEEP2(bq2); KEEP2(bq3); KEEP2(bq4);
    KEEP2(bq5); KEEP2(bq6); KEEP2(bq7); KEEP2(bq8); KEEP2(bt);
    KEEP2(wq0); KEEP2(wq1); KEEP2(wq2); KEEP2(wq3); KEEP2(wq4);
    KEEP2(wq5); KEEP2(wq6); KEEP2(wq7); KEEP2(wq8); KEEP2(wt);

#define G(acc, idx) { \
        uint4 r = *reinterpret_cast<const uint4*>( \
            reinterpret_cast<const char*>(tbl) + ((unsigned)(idx) << 4)); \
        acc[0] += bf16_lo(r.x); acc[1] += bf16_hi(r.x); \
        acc[2] += bf16_lo(r.y); acc[3] += bf16_hi(r.y); \
        acc[4] += bf16_lo(r.z); acc[5] += bf16_hi(r.z); \
        acc[6] += bf16_lo(r.w); acc[7] += bf16_hi(r.w); }

    float aB[8] = {0,0,0,0,0,0,0,0};
    float aW[8] = {0,0,0,0,0,0,0,0};

    // ---- interleaved B/W gathers: continuous LDS stream, 2 acc chains ----
    G(aB, bq0.x); G(aW, wq0.x); G(aB, bq0.y); G(aW, wq0.y);
    G(aB, bq1.x); G(aW, wq1.x); G(aB, bq1.y); G(aW, wq1.y);
    G(aB, bq2.x); G(aW, wq2.x); G(aB, bq2.y); G(aW, wq2.y);
    G(aB, bq3.x); G(aW, wq3.x); G(aB, bq3.y); G(aW, wq3.y);
    G(aB, bq4.x); G(aW, wq4.x); G(aB, bq4.y); G(aW, wq4.y);
    G(aB, bq5.x); G(aW, wq5.x); G(aB, bq5.y); G(aW, wq5.y);
    G(aB, bq6.x); G(aW, wq6.x); G(aB, bq6.y); G(aW, wq6.y);
    G(aB, bq7.x); G(aW, wq7.x); G(aB, bq7.y); G(aW, wq7.y);
    G(aB, bq8.x); G(aW, wq8.x); G(aB, bq8.y); G(aW, wq8.y);
    G(aB, h ? bt.y : bt.x);
    G(aW, h ? wt.y : wt.x);
#undef G

    // ---- pair-combine (8 shfl): lane h finalizes color h ----
    // lane h sends its partial of the OTHER color; receives peer's partial
    // of its own color.
    float fin[8];
#pragma unroll
    for (int k = 0; k < 8; ++k) {
        float send = h ? aB[k] : aW[k];
        float recv = __shfl_xor(send, 1);
        fin[k] = (h ? aW[k] : aB[k]) + recv + b1[k];
    }

    float dlo = 0.f, dhi = 0.f;
#pragma unroll
    for (int k = 0; k < 8; ++k) {
        float v = fminf(fmaxf(fin[k], 0.f), 1.f);
        dlo += v * w2[k];
        dhi += v * w2[8 + k];
    }

    // stm==0 -> order [black, white]; color h at slot 0 iff (s==0)==(h==0).
    const int s = stm[e];
    const float m = (((s == 0)) == (h == 0)) ? dlo : dhi;
    const float o = __shfl_xor(m, 1);
    if (h == 0) out[e] = m + o + b2[0];
}

extern "C" void kernel_launch(void* const* d_in, const int* in_sizes, int n_in,
                              void* d_out, int out_size, void* d_ws, size_t ws_size,
                              hipStream_t stream) {
    const int*   bfeat = (const int*)  d_in[0];
    const int*   wfeat = (const int*)  d_in[1];
    const int*   stm   = (const int*)  d_in[2];
    const float* w1    = (const float*)d_in[3];
    const float* b1    = (const float*)d_in[4];
    const float* w2    = (const float*)d_in[5];
    const float* b2    = (const float*)d_in[6];
    float* out = (float*)d_out;

    const int nbatch  = in_sizes[2];
    const long nthread = (long)nbatch * 2;
    const int grid = (int)((nthread + TPB - 1) / TPB);
    nnue_fwd<<<grid, TPB, 0, stream>>>(bfeat, wfeat, stm, w1, b1, w2, b2, out, nbatch);
}

// Round 11
// 22.005 us; speedup vs baseline: 1.8216x; 1.0837x over previous
//
#include <hip/hip_runtime.h>
#include <stdint.h>

#define NF   2344
#define ACCW 8
#define NA   38
#define TPB  512

__device__ __forceinline__ unsigned short f32_to_bf16(float f) {
    unsigned u = __float_as_uint(f);
    u += 0x7FFFu + ((u >> 16) & 1u);   // round-to-nearest-even
    return (unsigned short)(u >> 16);
}
__device__ __forceinline__ float bf16_lo(unsigned u) { return __uint_as_float(u << 16); }
__device__ __forceinline__ float bf16_hi(unsigned u) { return __uint_as_float(u & 0xFFFF0000u); }

// r6 structure (best measured: 21.95us, 32 waves/CU) with two micro-fixes:
// stm hoisted into the black load batch, and an 8-shfl pair-combine epilogue
// (shuffles ride the LDS pipe = the busiest pipe).
// 2 threads/elem (h = t&1). Lane h owns int2-slots {2j+h} of each color
// (pair covers contiguous 16B per instr); tail int2 loaded by both lanes,
// split .x/.y -> 38 full-exec gathers, no divergent tail.
__global__ __launch_bounds__(TPB, 4) void nnue_fwd(
    const int* __restrict__ bfeat, const int* __restrict__ wfeat,
    const int* __restrict__ stm,
    const float* __restrict__ w1, const float* __restrict__ b1,
    const float* __restrict__ w2, const float* __restrict__ b2,
    float* __restrict__ out, int nbatch)
{
    __shared__ unsigned short tbl[NF * ACCW];   // bf16 table, 16B/row (37.5 KB)

    for (int j = threadIdx.x; j < (NF * ACCW) / 4; j += TPB) {
        float4 v = reinterpret_cast<const float4*>(w1)[j];
        unsigned lo = (unsigned)f32_to_bf16(v.x) | ((unsigned)f32_to_bf16(v.y) << 16);
        unsigned hi = (unsigned)f32_to_bf16(v.z) | ((unsigned)f32_to_bf16(v.w) << 16);
        reinterpret_cast<uint2*>(tbl)[j] = make_uint2(lo, hi);
    }
    __syncthreads();

    const int t = blockIdx.x * TPB + threadIdx.x;
    const int e = t >> 1;
    const int h = t & 1;
    if (e >= nbatch) return;

    const int* __restrict__ bp = bfeat + (long)e * NA;
    const int* __restrict__ wp = wfeat + (long)e * NA;

#define G(acc, idx) { \
        uint4 r = *reinterpret_cast<const uint4*>( \
            reinterpret_cast<const char*>(tbl) + ((unsigned)(idx) << 4)); \
        acc[0] += bf16_lo(r.x); acc[1] += bf16_hi(r.x); \
        acc[2] += bf16_lo(r.y); acc[3] += bf16_hi(r.y); \
        acc[4] += bf16_lo(r.z); acc[5] += bf16_hi(r.z); \
        acc[6] += bf16_lo(r.w); acc[7] += bf16_hi(r.w); }

    float accB[8] = {0,0,0,0,0,0,0,0};
    float accW[8] = {0,0,0,0,0,0,0,0};
    int s;

    // ---- black phase (stm rides in the same load batch) ----
    {
        int2 q[9];
#pragma unroll
        for (int j = 0; j < 9; ++j)
            q[j] = *reinterpret_cast<const int2*>(bp + 4 * j + 2 * h);
        const int2 qt = *reinterpret_cast<const int2*>(bp + 36);  // shared slot
        s = stm[e];
#pragma unroll
        for (int j = 0; j < 9; ++j) { G(accB, q[j].x); G(accB, q[j].y); }
        G(accB, h ? qt.y : qt.x);
    }

    asm volatile("" ::: "memory");   // keep the two phases' live sets separate

    // ---- white phase ----
    {
        int2 q[9];
#pragma unroll
        for (int j = 0; j < 9; ++j)
            q[j] = *reinterpret_cast<const int2*>(wp + 4 * j + 2 * h);
        const int2 qt = *reinterpret_cast<const int2*>(wp + 36);
#pragma unroll
        for (int j = 0; j < 9; ++j) { G(accW, q[j].x); G(accW, q[j].y); }
        G(accW, h ? qt.y : qt.x);
    }
#undef G

    // ---- pair-combine (8 shfl): lane h finalizes color h (0=B, 1=W) ----
    float fin[8];
#pragma unroll
    for (int k = 0; k < 8; ++k) {
        float send = h ? accB[k] : accW[k];   // partial of the OTHER color
        float recv = __shfl_xor(send, 1);     // peer's partial of MY color
        fin[k] = (h ? accW[k] : accB[k]) + recv + b1[k];
    }

    float dlo = 0.f, dhi = 0.f;
#pragma unroll
    for (int k = 0; k < 8; ++k) {
        float v = fminf(fmaxf(fin[k], 0.f), 1.f);
        dlo += v * w2[k];
        dhi += v * w2[8 + k];
    }

    // stm==0 -> order [black, white]; color h sits at slot 0 iff (s==0)==(h==0).
    const float m = (((s == 0)) == (h == 0)) ? dlo : dhi;
    const float o = __shfl_xor(m, 1);
    if (h == 0) out[e] = m + o + b2[0];
}

extern "C" void kernel_launch(void* const* d_in, const int* in_sizes, int n_in,
                              void* d_out, int out_size, void* d_ws, size_t ws_size,
                              hipStream_t stream) {
    const int*   bfeat = (const int*)  d_in[0];
    const int*   wfeat = (const int*)  d_in[1];
    const int*   stm   = (const int*)  d_in[2];
    const float* w1    = (const float*)d_in[3];
    const float* b1    = (const float*)d_in[4];
    const float* w2    = (const float*)d_in[5];
    const float* b2    = (const float*)d_in[6];
    float* out = (float*)d_out;

    const int nbatch  = in_sizes[2];
    const long nthread = (long)nbatch * 2;
    const int grid = (int)((nthread + TPB - 1) / TPB);
    nnue_fwd<<<grid, TPB, 0, stream>>>(bfeat, wfeat, stm, w1, b1, w2, b2, out, nbatch);
}